// Round 1
// baseline (436.887 us; speedup 1.0000x reference)
//
#include <hip/hip_runtime.h>

#define KCAPS 10
#define OC    16
#define IC    256
#define HWSZ  36
#define PRIM  72
#define PD    8
#define EDIM  16
#define NITER 3

// LDS float-offsets (dynamic shared memory)
#define XT_STRIDE 260                  // padded row stride for x_t[hw][c]
#define U_STRIDE  17                   // padded u row [k][p][17]
#define CAPS_OFF  12240                // region1 = max(36*260=9360, 720*17=12240)
#define TOTAL_F   (12240 + 5760)       // region1 + caps region (routing overlays caps)

__global__ __launch_bounds__(256, 2)
void caps_fused(const float* __restrict__ x, const float* __restrict__ conv_w,
                const float* __restrict__ conv_b, const float* __restrict__ wts,
                float* __restrict__ out) {
    extern __shared__ float lds[];
    float* xt   = lds;                  // [36][260]   (phase 0-1)
    float* u    = lds;                  // [720][17]   (phase 2+, overwrites xt)
    float* caps = lds + CAPS_OFF;       // [5760]      (phase 1-2)
    // routing buffers overlay caps region (alive only after phase 2):
    float* b_s     = lds + CAPS_OFF;        // 720
    float* c_s     = b_s + 720;             // 720
    float* v_s     = c_s + 720;             // 160
    float* scale_s = v_s + 160;             // 10

    const int t  = threadIdx.x;
    const int bb = blockIdx.x;
    const float* xg = x + (size_t)bb * (IC * HWSZ);

    // ---- phase 0: stage x transposed [hw][c] (36 divisible by 4 -> float4 rows per c)
    for (int j = t; j < (IC * HWSZ) / 4; j += 256) {
        float4 xv = reinterpret_cast<const float4*>(xg)[j];
        int c = j / 9, hw0 = (j % 9) * 4;
        float* dst = xt + hw0 * XT_STRIDE + c;
        dst[0]             = xv.x;
        dst[XT_STRIDE]     = xv.y;
        dst[2 * XT_STRIDE] = xv.z;
        dst[3 * XT_STRIDE] = xv.w;
    }
    __syncthreads();

    // ---- phase 1: caps[k][o*36+hw] = sum_c x[c][hw]*conv_w[k][o][c] + conv_b[k][o]
    for (int idx = t; idx < KCAPS * OC * HWSZ; idx += 256) {
        int k = idx / (OC * HWSZ);
        int r = idx % (OC * HWSZ);
        int o = r / HWSZ, hw = r % HWSZ;
        const float4* wrow = reinterpret_cast<const float4*>(conv_w + (k * OC + o) * IC);
        const float4* xrow = reinterpret_cast<const float4*>(xt + hw * XT_STRIDE);
        float a0 = 0.f, a1 = 0.f, a2 = 0.f, a3 = 0.f;
        #pragma unroll 8
        for (int c4 = 0; c4 < IC / 4; ++c4) {
            float4 wv = wrow[c4];
            float4 xv = xrow[c4];
            a0 = fmaf(wv.x, xv.x, a0);
            a1 = fmaf(wv.y, xv.y, a1);
            a2 = fmaf(wv.z, xv.z, a2);
            a3 = fmaf(wv.w, xv.w, a3);
        }
        caps[idx] = (a0 + a1) + (a2 + a3) + conv_b[k * OC + o];
    }
    __syncthreads();

    // ---- phase 2: u[k][p][e] = sum_d caps[k][p*8+d] * wts[k][p][d][e]
    for (int task = t; task < KCAPS * PRIM; task += 256) {
        int k = task / PRIM, p = task % PRIM;
        float pv[PD];
        #pragma unroll
        for (int d = 0; d < PD; ++d) pv[d] = caps[k * (OC * HWSZ) + p * PD + d];
        float acc[EDIM] = {};
        const float4* wr = reinterpret_cast<const float4*>(wts + (size_t)(k * PRIM + p) * PD * EDIM);
        #pragma unroll
        for (int d = 0; d < PD; ++d) {
            #pragma unroll
            for (int e4 = 0; e4 < 4; ++e4) {
                float4 wv = wr[d * 4 + e4];
                acc[e4 * 4 + 0] = fmaf(pv[d], wv.x, acc[e4 * 4 + 0]);
                acc[e4 * 4 + 1] = fmaf(pv[d], wv.y, acc[e4 * 4 + 1]);
                acc[e4 * 4 + 2] = fmaf(pv[d], wv.z, acc[e4 * 4 + 2]);
                acc[e4 * 4 + 3] = fmaf(pv[d], wv.w, acc[e4 * 4 + 3]);
            }
        }
        float* urow = u + task * U_STRIDE;
        #pragma unroll
        for (int e = 0; e < EDIM; ++e) urow[e] = acc[e];
    }
    __syncthreads();   // after this, caps dead; routing buffers may overlay

    // ---- phase 3: dynamic routing (all fp32)
    for (int i = t; i < KCAPS * PRIM; i += 256) b_s[i] = 0.f;
    __syncthreads();

    for (int it = 0; it < NITER; ++it) {
        // softmax over k (axis=1) per primary p
        if (t < PRIM) {
            float bv[KCAPS];
            float m = -1e30f;
            #pragma unroll
            for (int k = 0; k < KCAPS; ++k) { bv[k] = b_s[k * PRIM + t]; m = fmaxf(m, bv[k]); }
            float sum = 0.f;
            #pragma unroll
            for (int k = 0; k < KCAPS; ++k) { bv[k] = __expf(bv[k] - m); sum += bv[k]; }
            float inv = 1.f / sum;
            #pragma unroll
            for (int k = 0; k < KCAPS; ++k) c_s[k * PRIM + t] = bv[k] * inv;
        }
        __syncthreads();

        // s[k][e] = sum_p c[k][p] * u[k][p][e]
        if (t < KCAPS * EDIM) {
            int k = t / EDIM, e = t % EDIM;
            float s = 0.f;
            for (int p = 0; p < PRIM; ++p)
                s = fmaf(c_s[k * PRIM + p], u[(k * PRIM + p) * U_STRIDE + e], s);
            v_s[t] = s;
        }
        __syncthreads();

        // squash scale per k
        if (t < KCAPS) {
            float sq = 0.f;
            #pragma unroll
            for (int e = 0; e < EDIM; ++e) { float sv = v_s[t * EDIM + e]; sq = fmaf(sv, sv, sq); }
            scale_s[t] = (sq / (1.f + sq)) * rsqrtf(sq + 1e-8f);
        }
        __syncthreads();

        if (t < KCAPS * EDIM) v_s[t] *= scale_s[t / EDIM];
        __syncthreads();

        // agreement update (skip on last iteration — b unused afterwards)
        if (it < NITER - 1) {
            for (int task = t; task < KCAPS * PRIM; task += 256) {
                int k = task / PRIM;
                float dot = 0.f;
                const float* ur = u + task * U_STRIDE;
                const float* vr = v_s + k * EDIM;
                #pragma unroll
                for (int e = 0; e < EDIM; ++e) dot = fmaf(ur[e], vr[e], dot);
                b_s[task] += dot;
            }
            __syncthreads();
        }
    }

    if (t < KCAPS * EDIM) out[(size_t)bb * (KCAPS * EDIM) + t] = v_s[t];
}

extern "C" void kernel_launch(void* const* d_in, const int* in_sizes, int n_in,
                              void* d_out, int out_size, void* d_ws, size_t ws_size,
                              hipStream_t stream) {
    const float* x  = (const float*)d_in[0];
    const float* cw = (const float*)d_in[1];
    const float* cb = (const float*)d_in[2];
    const float* wt = (const float*)d_in[3];
    float* out = (float*)d_out;

    const int B = in_sizes[0] / (IC * HWSZ);   // 2048
    const size_t smem = TOTAL_F * sizeof(float);  // 72000 B
    hipFuncSetAttribute((const void*)caps_fused, hipFuncAttributeMaxDynamicSharedMemorySize, (int)smem);
    hipLaunchKernelGGL(caps_fused, dim3(B), dim3(256), smem, stream, x, cw, cb, wt, out);
}

// Round 2
// 165.781 us; speedup vs baseline: 2.6353x; 2.6353x over previous
//
#include <hip/hip_runtime.h>
#include <stdint.h>

#define KCAPS 10
#define OC    16
#define IC    256
#define HWSZ  36
#define PRIM  72
#define PD    8
#define EDIM  16
#define NITER 3

typedef short bf16x8 __attribute__((ext_vector_type(8)));
typedef float f32x4  __attribute__((ext_vector_type(4)));

// LDS layout (bytes):
//   GEMM phase : xsh u32[48][132] (25344) | xsl u32[48][132] (25344) | whiT u32[160][20] (12800) | wloT u32[160][20] (12800)  = 76288
//   post-GEMM  : caps f32[160][41] (26240 overlays xsh+xsl head) | u f32[720][17] (48960, ends 75200)
//   routing    : b_s[720] c_s[720] v_s[160] scale[10] overlay [0,6440) (caps dead)
#define SMEM_BYTES 76288

__device__ __forceinline__ void bf_split(float v, unsigned short& hb, unsigned short& lb) {
    __bf16 h = (__bf16)v;
    float hf = (float)h;
    hb = __builtin_bit_cast(unsigned short, h);
    __bf16 l = (__bf16)(v - hf);
    lb = __builtin_bit_cast(unsigned short, l);
}

__device__ __forceinline__ f32x4 mfma16(bf16x8 a, bf16x8 b, f32x4 c) {
    return __builtin_amdgcn_mfma_f32_16x16x32_bf16(a, b, c, 0, 0, 0);
}

__global__ __launch_bounds__(256) void split_w_kernel(const float* __restrict__ w,
                                                      unsigned short* __restrict__ hi,
                                                      unsigned short* __restrict__ lo) {
    int i = blockIdx.x * 256 + threadIdx.x;
    if (i < KCAPS * OC * IC) {
        unsigned short hb, lb;
        bf_split(w[i], hb, lb);
        hi[i] = hb;
        lo[i] = lb;
    }
}

template<bool PRE>
__global__ __launch_bounds__(256, 2)
void caps_mfma(const float* __restrict__ x, const float* __restrict__ conv_w,
               const float* __restrict__ conv_b, const float* __restrict__ wts,
               const unsigned short* __restrict__ whi, const unsigned short* __restrict__ wlo,
               float* __restrict__ out) {
    extern __shared__ char smem[];
    uint32_t* xsh  = (uint32_t*)smem;          // [48][132] u32  == bf16 [48][264]
    uint32_t* xsl  = xsh + 48 * 132;
    uint32_t* whiT = xsl + 48 * 132;           // [160][20] u32 == bf16 [160][40]
    uint32_t* wloT = whiT + 160 * 20;
    const short* xshS = (const short*)xsh;
    const short* xslS = (const short*)xsl;
    const short* whiS = (const short*)whiT;
    const short* wloS = (const short*)wloT;
    float* caps    = (float*)smem;             // [160][41]
    float* u_s     = caps + 160 * 41;          // [720][17]
    float* b_s     = (float*)smem;             // routing overlays
    float* c_s     = b_s + 720;
    float* v_s     = c_s + 720;
    float* scale_s = v_s + 160;

    const int t   = threadIdx.x;
    const int bb  = blockIdx.x;
    const int wv  = t >> 6;
    const int ln  = t & 63;
    const int row = ln & 15;          // A-row / B-col / D-col index within tile
    const int g   = ln >> 4;          // k-group; D-row block
    const int nm  = (wv < 2) ? 3 : 2; // m-tiles per wave: {0,4,8},{1,5,9},{2,6},{3,7}

    const uint32_t* whi_u = (const uint32_t*)whi;
    const uint32_t* wlo_u = (const uint32_t*)wlo;

    // ---- phase 0a: stage x -> transposed bf16 hi/lo  xs[hw][c], stride 264 bf16
    {
        const float4* x4 = (const float4*)(x + (size_t)bb * (IC * HWSZ));
        for (int task = t; task < 1152; task += 256) {     // 128 c-pairs x 9 hw-quads
            int cp = task / 9, hq = task - cp * 9;
            float4 va = x4[(2 * cp) * 9 + hq];             // c = 2cp,   hw = 4hq..+3
            float4 vb = x4[(2 * cp + 1) * 9 + hq];         // c = 2cp+1
            int base = (4 * hq) * 132 + cp;
            unsigned short ha, la, hb, lb;
            bf_split(va.x, ha, la); bf_split(vb.x, hb, lb);
            xsh[base]       = (uint32_t)ha | ((uint32_t)hb << 16);
            xsl[base]       = (uint32_t)la | ((uint32_t)lb << 16);
            bf_split(va.y, ha, la); bf_split(vb.y, hb, lb);
            xsh[base + 132] = (uint32_t)ha | ((uint32_t)hb << 16);
            xsl[base + 132] = (uint32_t)la | ((uint32_t)lb << 16);
            bf_split(va.z, ha, la); bf_split(vb.z, hb, lb);
            xsh[base + 264] = (uint32_t)ha | ((uint32_t)hb << 16);
            xsl[base + 264] = (uint32_t)la | ((uint32_t)lb << 16);
            bf_split(va.w, ha, la); bf_split(vb.w, hb, lb);
            xsh[base + 396] = (uint32_t)ha | ((uint32_t)hb << 16);
            xsl[base + 396] = (uint32_t)la | ((uint32_t)lb << 16);
        }
        for (int i = t; i < 12 * 132; i += 256) {          // zero pad rows 36..47
            xsh[36 * 132 + i] = 0u;
            xsl[36 * 132 + i] = 0u;
        }
    }
    // ---- phase 0b: stage w k-tile 0 (hi+lo), [160][40] bf16 per half
    if (PRE) {
        for (int i = t; i < 5120; i += 256) {
            int half = (i >= 2560);
            int idx  = half ? i - 2560 : i;
            int m = idx >> 4, ci = idx & 15;
            uint32_t v = (half ? wlo_u : whi_u)[m * 128 + ci];
            (half ? wloT : whiT)[m * 20 + ci] = v;
        }
    } else {
        for (int q = t; q < 2560; q += 256) {
            int m = q >> 4, pq = q & 15;
            float2 v2 = *(const float2*)(conv_w + m * 256 + 2 * pq);
            unsigned short h0, l0, h1, l1;
            bf_split(v2.x, h0, l0); bf_split(v2.y, h1, l1);
            whiT[m * 20 + pq] = (uint32_t)h0 | ((uint32_t)h1 << 16);
            wloT[m * 20 + pq] = (uint32_t)l0 | ((uint32_t)l1 << 16);
        }
    }
    __syncthreads();

    // ---- phase 1: GEMM caps^T[hw][m] = x^T[hw][c] * w^T[c][m], 3-pass bf16 split
    f32x4 acc[3][3] = {};                // [mi][nt]
    uint32_t pf[20];
    float2   pf2[10];
    for (int kt = 0; kt < 8; ++kt) {
        if (kt < 7) {                    // issue next k-tile loads early (latency hides under MFMA)
            if (PRE) {
                #pragma unroll
                for (int j = 0; j < 20; ++j) {
                    int i = t + j * 256;
                    int half = (j >= 10);
                    int idx = half ? i - 2560 : i;
                    int m = idx >> 4, ci = idx & 15;
                    pf[j] = (half ? wlo_u : whi_u)[m * 128 + (kt + 1) * 16 + ci];
                }
            } else {
                #pragma unroll
                for (int j = 0; j < 10; ++j) {
                    int q = t + j * 256;
                    int m = q >> 4, pq = q & 15;
                    pf2[j] = *(const float2*)(conv_w + m * 256 + (kt + 1) * 32 + 2 * pq);
                }
            }
        }
        bf16x8 afh[3], afl[3], bfh[3], bfl[3];
        #pragma unroll
        for (int nt = 0; nt < 3; ++nt) {
            int o2 = (nt * 16 + row) * 264 + kt * 32 + g * 8;
            afh[nt] = *(const bf16x8*)(xshS + o2);
            afl[nt] = *(const bf16x8*)(xslS + o2);
        }
        #pragma unroll
        for (int mi = 0; mi < 3; ++mi) {
            if (mi < nm) {
                int o2 = ((wv + 4 * mi) * 16 + row) * 40 + g * 8;
                bfh[mi] = *(const bf16x8*)(whiS + o2);
                bfl[mi] = *(const bf16x8*)(wloS + o2);
            }
        }
        #pragma unroll
        for (int mi = 0; mi < 3; ++mi) {
            if (mi < nm) {
                #pragma unroll
                for (int nt = 0; nt < 3; ++nt) {
                    acc[mi][nt] = mfma16(afh[nt], bfh[mi], acc[mi][nt]);
                    acc[mi][nt] = mfma16(afl[nt], bfh[mi], acc[mi][nt]);
                    acc[mi][nt] = mfma16(afh[nt], bfl[mi], acc[mi][nt]);
                }
            }
        }
        __syncthreads();                 // all reads of current w-tile done
        if (kt < 7) {
            if (PRE) {
                #pragma unroll
                for (int j = 0; j < 20; ++j) {
                    int i = t + j * 256;
                    int half = (j >= 10);
                    int idx = half ? i - 2560 : i;
                    int m = idx >> 4, ci = idx & 15;
                    (half ? wloT : whiT)[m * 20 + ci] = pf[j];
                }
            } else {
                #pragma unroll
                for (int j = 0; j < 10; ++j) {
                    int q = t + j * 256;
                    int m = q >> 4, pq = q & 15;
                    unsigned short h0, l0, h1, l1;
                    bf_split(pf2[j].x, h0, l0); bf_split(pf2[j].y, h1, l1);
                    whiT[m * 20 + pq] = (uint32_t)h0 | ((uint32_t)h1 << 16);
                    wloT[m * 20 + pq] = (uint32_t)l0 | ((uint32_t)l1 << 16);
                }
            }
            __syncthreads();             // new tile visible
        }
    }

    // ---- C-write (+bias) into caps overlay (xs region dead after last sync)
    #pragma unroll
    for (int mi = 0; mi < 3; ++mi) {
        if (mi < nm) {
            int m = (wv + 4 * mi) * 16 + row;        // D-col = m
            float bias = conv_b[m];
            #pragma unroll
            for (int nt = 0; nt < 3; ++nt) {
                #pragma unroll
                for (int r = 0; r < 4; ++r) {
                    int hw = nt * 16 + g * 4 + r;    // D-row = hw
                    if (hw < 36) caps[m * 41 + hw] = acc[mi][nt][r] + bias;
                }
            }
        }
    }
    __syncthreads();

    // ---- phase 2: u[k][p][e] = sum_d caps[k][p*8+d] * wts[k][p][d][e]   (wts f32)
    for (int task = t; task < KCAPS * PRIM; task += 256) {
        int k = task / PRIM, p = task - k * PRIM;
        float pv[PD];
        int flat = p * PD;
        int o  = flat / HWSZ;
        int hw = flat - o * HWSZ;
        #pragma unroll
        for (int d = 0; d < PD; ++d) {
            pv[d] = caps[(k * OC + o) * 41 + hw];
            if (++hw == HWSZ) { hw = 0; ++o; }
        }
        const float4* wp = (const float4*)(wts + (size_t)(k * PRIM + p) * (PD * EDIM));
        float au[EDIM] = {};
        #pragma unroll
        for (int d = 0; d < PD; ++d) {
            #pragma unroll
            for (int e4 = 0; e4 < 4; ++e4) {
                float4 w4 = wp[d * 4 + e4];
                au[e4 * 4 + 0] = fmaf(pv[d], w4.x, au[e4 * 4 + 0]);
                au[e4 * 4 + 1] = fmaf(pv[d], w4.y, au[e4 * 4 + 1]);
                au[e4 * 4 + 2] = fmaf(pv[d], w4.z, au[e4 * 4 + 2]);
                au[e4 * 4 + 3] = fmaf(pv[d], w4.w, au[e4 * 4 + 3]);
            }
        }
        float* ur = u_s + task * 17;
        #pragma unroll
        for (int e = 0; e < EDIM; ++e) ur[e] = au[e];
    }
    __syncthreads();                      // caps dead after this

    // ---- phase 3: dynamic routing (fp32)
    for (int i = t; i < KCAPS * PRIM; i += 256) b_s[i] = 0.f;
    __syncthreads();

    for (int it = 0; it < NITER; ++it) {
        if (t < PRIM) {                   // softmax over k per primary p
            float bv[KCAPS];
            float m = -1e30f;
            #pragma unroll
            for (int k = 0; k < KCAPS; ++k) { bv[k] = b_s[k * PRIM + t]; m = fmaxf(m, bv[k]); }
            float sum = 0.f;
            #pragma unroll
            for (int k = 0; k < KCAPS; ++k) { bv[k] = __expf(bv[k] - m); sum += bv[k]; }
            float inv = 1.f / sum;
            #pragma unroll
            for (int k = 0; k < KCAPS; ++k) c_s[k * PRIM + t] = bv[k] * inv;
        }
        __syncthreads();

        if (t < KCAPS * EDIM) {           // s[k][e] = sum_p c*u
            int k = t / EDIM, e = t - (t / EDIM) * EDIM;
            float s = 0.f;
            for (int p = 0; p < PRIM; ++p)
                s = fmaf(c_s[k * PRIM + p], u_s[(k * PRIM + p) * 17 + e], s);
            v_s[t] = s;
        }
        __syncthreads();

        if (t < KCAPS) {                  // squash scale
            float sq = 0.f;
            #pragma unroll
            for (int e = 0; e < EDIM; ++e) { float sv = v_s[t * EDIM + e]; sq = fmaf(sv, sv, sq); }
            scale_s[t] = (sq / (1.f + sq)) * rsqrtf(sq + 1e-8f);
        }
        __syncthreads();

        if (t < KCAPS * EDIM) v_s[t] *= scale_s[t / EDIM];
        __syncthreads();

        if (it < NITER - 1) {             // agreement update
            for (int task = t; task < KCAPS * PRIM; task += 256) {
                int k = task / PRIM;
                float dot = 0.f;
                const float* ur = u_s + task * 17;
                const float* vr = v_s + k * EDIM;
                #pragma unroll
                for (int e = 0; e < EDIM; ++e) dot = fmaf(ur[e], vr[e], dot);
                b_s[task] += dot;
            }
            __syncthreads();
        }
    }

    if (t < KCAPS * EDIM) out[(size_t)bb * (KCAPS * EDIM) + t] = v_s[t];
}

extern "C" void kernel_launch(void* const* d_in, const int* in_sizes, int n_in,
                              void* d_out, int out_size, void* d_ws, size_t ws_size,
                              hipStream_t stream) {
    const float* x  = (const float*)d_in[0];
    const float* cw = (const float*)d_in[1];
    const float* cb = (const float*)d_in[2];
    const float* wt = (const float*)d_in[3];
    float* out = (float*)d_out;
    const int B = in_sizes[0] / (IC * HWSZ);   // 2048
    const size_t smem = SMEM_BYTES;

    bool pre = (d_ws != nullptr) && (ws_size >= (size_t)(2 * KCAPS * OC * IC * sizeof(unsigned short)));
    if (pre) {
        unsigned short* whi = (unsigned short*)d_ws;
        unsigned short* wlo = whi + KCAPS * OC * IC;
        hipLaunchKernelGGL(split_w_kernel, dim3((KCAPS * OC * IC + 255) / 256), dim3(256), 0, stream, cw, whi, wlo);
        auto* kfn = &caps_mfma<true>;
        hipFuncSetAttribute(reinterpret_cast<const void*>(kfn),
                            hipFuncAttributeMaxDynamicSharedMemorySize, (int)smem);
        hipLaunchKernelGGL(caps_mfma<true>, dim3(B), dim3(256), smem, stream, x, cw, cb, wt, whi, wlo, out);
    } else {
        auto* kfn = &caps_mfma<false>;
        hipFuncSetAttribute(reinterpret_cast<const void*>(kfn),
                            hipFuncAttributeMaxDynamicSharedMemorySize, (int)smem);
        hipLaunchKernelGGL(caps_mfma<false>, dim3(B), dim3(256), smem, stream, x, cw, cb, wt,
                           (const unsigned short*)nullptr, (const unsigned short*)nullptr, out);
    }
}

// Round 3
// 108.721 us; speedup vs baseline: 4.0184x; 1.5248x over previous
//
#include <hip/hip_runtime.h>
#include <stdint.h>

#define KCAPS 10
#define OC    16
#define IC    256
#define HWSZ  36
#define PRIM  72
#define PD    8
#define EDIM  16
#define NITER 3

typedef short bf16x8 __attribute__((ext_vector_type(8)));
typedef float f32x4  __attribute__((ext_vector_type(4)));

// LDS (bytes):
//   GEMM : xsh u32[48][132] (25344) | xsl u32[48][132] (25344)        = [0, 50688)
//   caps : f32 [10][584] flat (23360)                                  = [50688, 74048)
//   u_t  : f32 [16][720] (46080) overlays xs after GEMM                = [0, 46080)
//   rout : b[720] c[720] v[160] scale[10] overlay caps after phase 2
#define SMEM_BYTES 74048
#define CAPS_F 12672            // float offset of caps region

// prep: bf16 hi/lo split of conv_w + coalesced-transpose of wts
__global__ __launch_bounds__(256)
void prep_kernel(const float* __restrict__ w, const float* __restrict__ wts,
                 unsigned short* __restrict__ hi, unsigned short* __restrict__ lo,
                 float4* __restrict__ wtsT4) {
    int i = blockIdx.x * 256 + threadIdx.x;
    if (i < KCAPS * OC * IC) {
        float v = w[i];
        __bf16 h = (__bf16)v;
        hi[i] = __builtin_bit_cast(unsigned short, h);
        __bf16 l = (__bf16)(v - (float)h);
        lo[i] = __builtin_bit_cast(unsigned short, l);
    }
    if (i < KCAPS * PD * 4 * PRIM) {      // 23040 float4 tasks
        int p = i % PRIM;
        int r = i / PRIM;
        int e4 = r & 3; r >>= 2;
        int d  = r & 7;
        int k  = r >> 3;
        wtsT4[i] = *(const float4*)(wts + (size_t)(((k * PRIM + p) * PD + d) * EDIM + e4 * 4));
    }
}

__device__ __forceinline__ void bf_split(float v, unsigned short& hb, unsigned short& lb) {
    __bf16 h = (__bf16)v;
    hb = __builtin_bit_cast(unsigned short, h);
    __bf16 l = (__bf16)(v - (float)h);
    lb = __builtin_bit_cast(unsigned short, l);
}

__device__ __forceinline__ f32x4 mfma16(bf16x8 a, bf16x8 b, f32x4 c) {
    return __builtin_amdgcn_mfma_f32_16x16x32_bf16(a, b, c, 0, 0, 0);
}

template<bool PRE>
__global__ __launch_bounds__(512, 4)
void caps_mfma(const float* __restrict__ x, const float* __restrict__ conv_w,
               const float* __restrict__ conv_b, const float* __restrict__ wts,
               const unsigned short* __restrict__ whi, const unsigned short* __restrict__ wlo,
               const float4* __restrict__ wtsT4, float* __restrict__ out) {
    extern __shared__ char smem[];
    uint32_t* xsh = (uint32_t*)smem;                  // [48][132]
    uint32_t* xsl = xsh + 48 * 132;
    const short* xshS = (const short*)xsh;
    const short* xslS = (const short*)xsl;
    float* u_t  = (float*)smem;                       // [16][720], overlays xs
    float* caps = (float*)smem + CAPS_F;              // [10][584] flat
    float* b_s     = (float*)smem + CAPS_F;           // routing overlays caps
    float* c_s     = b_s + 720;
    float* v_s     = c_s + 720;
    float* scale_s = v_s + 160;

    const int t   = threadIdx.x;
    const int bb  = blockIdx.x;
    const int wv  = t >> 6;             // 0..7
    const int ln  = t & 63;
    const int row = ln & 15;
    const int g   = ln >> 4;
    const int nm  = (wv < 2) ? 2 : 1;   // m-tiles per wave: {wv, wv+8} or {wv}

    // ---- phase 0: stage x transposed -> bf16 hi/lo, [48 hw][264 c] (rows 36-47 uninit; their D-rows are discarded)
    {
        const float4* x4 = (const float4*)(x + (size_t)bb * (IC * HWSZ));
        for (int task = t; task < 1152; task += 512) {   // 128 c-pairs x 9 hw-quads
            int cp = task / 9, hq = task - cp * 9;
            float4 va = x4[(2 * cp) * 9 + hq];
            float4 vb = x4[(2 * cp + 1) * 9 + hq];
            int base = (4 * hq) * 132 + cp;
            unsigned short ha, la, hb, lb;
            bf_split(va.x, ha, la); bf_split(vb.x, hb, lb);
            xsh[base]       = (uint32_t)ha | ((uint32_t)hb << 16);
            xsl[base]       = (uint32_t)la | ((uint32_t)lb << 16);
            bf_split(va.y, ha, la); bf_split(vb.y, hb, lb);
            xsh[base + 132] = (uint32_t)ha | ((uint32_t)hb << 16);
            xsl[base + 132] = (uint32_t)la | ((uint32_t)lb << 16);
            bf_split(va.z, ha, la); bf_split(vb.z, hb, lb);
            xsh[base + 264] = (uint32_t)ha | ((uint32_t)hb << 16);
            xsl[base + 264] = (uint32_t)la | ((uint32_t)lb << 16);
            bf_split(va.w, ha, la); bf_split(vb.w, hb, lb);
            xsh[base + 396] = (uint32_t)ha | ((uint32_t)hb << 16);
            xsl[base + 396] = (uint32_t)la | ((uint32_t)lb << 16);
        }
    }
    __syncthreads();

    // ---- phase 1: GEMM caps^T[hw][m] = x^T[hw][c] * w[m][c], bf16 3-pass, NO barriers
    f32x4 acc[2][3] = {};
    #pragma unroll 2
    for (int kt = 0; kt < 8; ++kt) {
        bf16x8 afh[3], afl[3], bfh[2], bfl[2];
        #pragma unroll
        for (int nt = 0; nt < 3; ++nt) {
            int o2 = (nt * 16 + row) * 264 + kt * 32 + g * 8;
            afh[nt] = *(const bf16x8*)(xshS + o2);
            afl[nt] = *(const bf16x8*)(xslS + o2);
        }
        #pragma unroll
        for (int mi = 0; mi < 2; ++mi) {
            if (mi < nm) {
                int m = (wv + 8 * mi) * 16 + row;
                int off = m * 256 + kt * 32 + g * 8;
                if (PRE) {
                    bfh[mi] = *(const bf16x8*)(whi + off);
                    bfl[mi] = *(const bf16x8*)(wlo + off);
                } else {
                    const float* wrow = conv_w + off;
                    float4 wa = *(const float4*)wrow;
                    float4 wb2 = *(const float4*)(wrow + 4);
                    unsigned short h, l;
                    bf16x8 bh, bl;
                    bf_split(wa.x, h, l); bh[0] = (short)h; bl[0] = (short)l;
                    bf_split(wa.y, h, l); bh[1] = (short)h; bl[1] = (short)l;
                    bf_split(wa.z, h, l); bh[2] = (short)h; bl[2] = (short)l;
                    bf_split(wa.w, h, l); bh[3] = (short)h; bl[3] = (short)l;
                    bf_split(wb2.x, h, l); bh[4] = (short)h; bl[4] = (short)l;
                    bf_split(wb2.y, h, l); bh[5] = (short)h; bl[5] = (short)l;
                    bf_split(wb2.z, h, l); bh[6] = (short)h; bl[6] = (short)l;
                    bf_split(wb2.w, h, l); bh[7] = (short)h; bl[7] = (short)l;
                    bfh[mi] = bh; bfl[mi] = bl;
                }
            }
        }
        #pragma unroll
        for (int mi = 0; mi < 2; ++mi) {
            if (mi < nm) {
                #pragma unroll
                for (int nt = 0; nt < 3; ++nt) {
                    acc[mi][nt] = mfma16(afh[nt], bfh[mi], acc[mi][nt]);
                    acc[mi][nt] = mfma16(afl[nt], bfh[mi], acc[mi][nt]);
                    acc[mi][nt] = mfma16(afh[nt], bfl[mi], acc[mi][nt]);
                }
            }
        }
    }

    // ---- C-write (+bias): caps[k=mt][o=row][hw], region disjoint from xs -> no barrier needed before
    #pragma unroll
    for (int mi = 0; mi < 2; ++mi) {
        if (mi < nm) {
            int mt = wv + 8 * mi;                    // capsule k == m-tile
            float bias = conv_b[mt * 16 + row];
            #pragma unroll
            for (int nt = 0; nt < 3; ++nt) {
                #pragma unroll
                for (int r = 0; r < 4; ++r) {
                    int hw = nt * 16 + g * 4 + r;
                    if (hw < 36) caps[mt * 584 + row * 36 + hw] = acc[mi][nt][r] + bias;
                }
            }
        }
    }
    __syncthreads();   // caps complete; xs dead -> u_t may overlay

    // ---- phase 2: u[k][p][e] = sum_d prim[d] * wts[k][p][d][e]  (wts f32), u stored transposed
    for (int task = t; task < KCAPS * PRIM; task += 512) {
        int k = task / PRIM, p = task - k * PRIM;
        const float4* cp4 = (const float4*)(caps + k * 584 + p * 8);
        float4 q0 = cp4[0], q1 = cp4[1];
        float pv[PD] = {q0.x, q0.y, q0.z, q0.w, q1.x, q1.y, q1.z, q1.w};
        float au[EDIM] = {};
        if (PRE) {
            const float4* wb = wtsT4 + (size_t)k * 2304 + p;   // [(d*4+e4)*72] stride, coalesced over p
            #pragma unroll
            for (int d = 0; d < PD; ++d) {
                #pragma unroll
                for (int e4 = 0; e4 < 4; ++e4) {
                    float4 w4 = wb[(d * 4 + e4) * PRIM];
                    au[e4 * 4 + 0] = fmaf(pv[d], w4.x, au[e4 * 4 + 0]);
                    au[e4 * 4 + 1] = fmaf(pv[d], w4.y, au[e4 * 4 + 1]);
                    au[e4 * 4 + 2] = fmaf(pv[d], w4.z, au[e4 * 4 + 2]);
                    au[e4 * 4 + 3] = fmaf(pv[d], w4.w, au[e4 * 4 + 3]);
                }
            }
        } else {
            const float4* wp = (const float4*)(wts + (size_t)(k * PRIM + p) * (PD * EDIM));
            #pragma unroll
            for (int d = 0; d < PD; ++d) {
                #pragma unroll
                for (int e4 = 0; e4 < 4; ++e4) {
                    float4 w4 = wp[d * 4 + e4];
                    au[e4 * 4 + 0] = fmaf(pv[d], w4.x, au[e4 * 4 + 0]);
                    au[e4 * 4 + 1] = fmaf(pv[d], w4.y, au[e4 * 4 + 1]);
                    au[e4 * 4 + 2] = fmaf(pv[d], w4.z, au[e4 * 4 + 2]);
                    au[e4 * 4 + 3] = fmaf(pv[d], w4.w, au[e4 * 4 + 3]);
                }
            }
        }
        #pragma unroll
        for (int e = 0; e < EDIM; ++e) u_t[e * 720 + task] = au[e];
    }
    __syncthreads();   // caps dead -> routing buffers may overlay

    // ---- phase 3: dynamic routing
    for (int i = t; i < KCAPS * PRIM; i += 512) b_s[i] = 0.f;
    __syncthreads();

    for (int it = 0; it < NITER; ++it) {
        if (t < PRIM) {                  // softmax over k per primary
            float bv[KCAPS];
            float m = -1e30f;
            #pragma unroll
            for (int k = 0; k < KCAPS; ++k) { bv[k] = b_s[k * PRIM + t]; m = fmaxf(m, bv[k]); }
            float sum = 0.f;
            #pragma unroll
            for (int k = 0; k < KCAPS; ++k) { bv[k] = __expf(bv[k] - m); sum += bv[k]; }
            float inv = 1.f / sum;
            #pragma unroll
            for (int k = 0; k < KCAPS; ++k) c_s[k * PRIM + t] = bv[k] * inv;
        }
        __syncthreads();

        if (t < KCAPS * EDIM) {          // s[k][e] = sum_p c*u
            int k = t >> 4, e = t & 15;
            float s = 0.f;
            const float* ur = u_t + e * 720 + k * PRIM;
            const float* cr = c_s + k * PRIM;
            for (int p = 0; p < PRIM; ++p) s = fmaf(cr[p], ur[p], s);
            v_s[t] = s;
        }
        __syncthreads();

        if (t < KCAPS) {                 // squash scale
            float sq = 0.f;
            #pragma unroll
            for (int e = 0; e < EDIM; ++e) { float sv = v_s[t * EDIM + e]; sq = fmaf(sv, sv, sq); }
            scale_s[t] = (sq / (1.f + sq)) * rsqrtf(sq + 1e-8f);
        }
        __syncthreads();

        if (t < KCAPS * EDIM) v_s[t] *= scale_s[t >> 4];
        __syncthreads();

        if (it < NITER - 1) {            // agreement
            for (int task = t; task < KCAPS * PRIM; task += 512) {
                int k = task / PRIM;
                float dot = 0.f;
                const float* vr = v_s + k * EDIM;
                #pragma unroll
                for (int e = 0; e < EDIM; ++e) dot = fmaf(u_t[e * 720 + task], vr[e], dot);
                b_s[task] += dot;
            }
            __syncthreads();
        }
    }

    if (t < KCAPS * EDIM) out[(size_t)bb * (KCAPS * EDIM) + t] = v_s[t];
}

extern "C" void kernel_launch(void* const* d_in, const int* in_sizes, int n_in,
                              void* d_out, int out_size, void* d_ws, size_t ws_size,
                              hipStream_t stream) {
    const float* x  = (const float*)d_in[0];
    const float* cw = (const float*)d_in[1];
    const float* cb = (const float*)d_in[2];
    const float* wt = (const float*)d_in[3];
    float* out = (float*)d_out;
    const int B = in_sizes[0] / (IC * HWSZ);   // 2048
    const size_t smem = SMEM_BYTES;

    const size_t W_U16 = (size_t)KCAPS * OC * IC;                  // 40960
    const size_t need = 2 * W_U16 * sizeof(unsigned short)         // whi+wlo 163840
                      + (size_t)KCAPS * PD * 4 * PRIM * 16;        // wtsT4  368640
    bool pre = (d_ws != nullptr) && (ws_size >= need);
    if (pre) {
        unsigned short* whi = (unsigned short*)d_ws;
        unsigned short* wlo = whi + W_U16;
        float4* wtsT4 = (float4*)(wlo + W_U16);
        hipLaunchKernelGGL(prep_kernel, dim3(160), dim3(256), 0, stream, cw, wt, whi, wlo, wtsT4);
        hipFuncSetAttribute(reinterpret_cast<const void*>(&caps_mfma<true>),
                            hipFuncAttributeMaxDynamicSharedMemorySize, (int)smem);
        hipLaunchKernelGGL(caps_mfma<true>, dim3(B), dim3(512), smem, stream,
                           x, cw, cb, wt, whi, wlo, wtsT4, out);
    } else {
        hipFuncSetAttribute(reinterpret_cast<const void*>(&caps_mfma<false>),
                            hipFuncAttributeMaxDynamicSharedMemorySize, (int)smem);
        hipLaunchKernelGGL(caps_mfma<false>, dim3(B), dim3(512), smem, stream,
                           x, cw, cb, wt,
                           (const unsigned short*)nullptr, (const unsigned short*)nullptr,
                           (const float4*)nullptr, out);
    }
}